// Round 13
// baseline (271.605 us; speedup 1.0000x reference)
//
#include <hip/hip_runtime.h>
#include <hip/hip_bf16.h>
#include <math.h>

#define NEG 0.2f
#define NB_MAX 256
#define CAP 5120

typedef float f32x4 __attribute__((ext_vector_type(4)));
typedef _Float16 f16;
typedef _Float16 f16x2 __attribute__((ext_vector_type(2)));
typedef _Float16 f16x8 __attribute__((ext_vector_type(8)));
typedef unsigned u32x4 __attribute__((ext_vector_type(4)));

#if defined(__has_builtin)
#if __has_builtin(__builtin_amdgcn_fdot2)
#define HAVE_FDOT2 1
#endif
#endif

typedef __attribute__((address_space(3))) void as3_void;
typedef __attribute__((address_space(1))) const void as1_void;

__device__ __forceinline__ void gl_lds16(const void* g, void* l) {
    __builtin_amdgcn_global_load_lds((as1_void*)g, (as3_void*)l, 16, 0, 0);
}

__device__ __forceinline__ f16x8 nt_load8(const _Float16* p) {
    u32x4 v = __builtin_nontemporal_load((const u32x4*)p);
    return __builtin_bit_cast(f16x8, v);
}
__device__ __forceinline__ void nt_store8(_Float16* p, f16x8 w) {
    __builtin_nontemporal_store(__builtin_bit_cast(u32x4, w), (u32x4*)p);
}

// ---- stage one 128-row x 32-k fp16 tile (8KB, [128][64B] rows, slot^(row&3)
//      swizzle) into LDS via global_load_lds with pre-swizzled source.
__device__ __forceinline__ void stage16(const _Float16* __restrict__ src,
                                        int row_base, int row_max, int k0,
                                        char* lds, int tid) {
#pragma unroll
    for (int q = 0; q < 2; ++q) {
        int off = q * 4096 + tid * 16;
        int row = off >> 6;
        int slot = (off >> 4) & 3;
        int se = slot ^ (row & 3);
        int grow = row_base + row;
        if (grow > row_max) grow = row_max;
        gl_lds16(src + (size_t)grow * 256 + k0 + se * 8,
                 lds + q * 4096 + (tid >> 6) * 1024);   // wave-uniform LDS base
    }
}

// ---- same tile from an fp32 source: reg-staged load + cvt + ds_write (swizzled)
__device__ __forceinline__ void stage16_f32(const float* __restrict__ X,
                                            int row_base, int row_max, int k0,
                                            char* lds, int tid) {
#pragma unroll
    for (int u = 0; u < 4; ++u) {
        int unit = u * 256 + tid;                      // 8B units
        int r = unit >> 3, hu = unit & 7;
        int slot = hu >> 1, sub = (hu & 1) * 8;
        int se = slot ^ (r & 3);
        int grow = row_base + r;
        if (grow > row_max) grow = row_max;
        float4 v = *(const float4*)(X + (size_t)grow * 256 + k0 + se * 8 + (hu & 1) * 4);
        f16x2 p0 = {(f16)v.x, (f16)v.y};
        f16x2 p1 = {(f16)v.z, (f16)v.w};
        uint2 w;
        w.x = __builtin_bit_cast(unsigned, p0);
        w.y = __builtin_bit_cast(unsigned, p1);
        *(uint2*)(lds + r * 64 + slot * 16 + sub) = w;
    }
}

// ---- fp16 MFMA GEMM body: rows [128*(m_base+ml)) x [256,512] -> Af/Bf f16
//      128x128 tile, 4 waves, BK=32, double-buffered 32KB LDS, XCD-aware remap.
template <int SRC>
__device__ __forceinline__ void gemm_body(char* smem, int b, int m_base, int m_tiles,
                                          const float* __restrict__ Xf,
                                          const _Float16* __restrict__ X16,
                                          const _Float16* __restrict__ Wt,
                                          const float* __restrict__ bl,
                                          const float* __restrict__ br,
                                          _Float16* __restrict__ Af,
                                          _Float16* __restrict__ Bf, int M) {
    int cx = b & 7, rr = b >> 3;                      // cx = XCD slot
    int ml = (rr >> 2) * 8 + cx;
    int n_blk = rr & 3;
    if (ml >= m_tiles) return;
    int tid = threadIdx.x;
    int wave = tid >> 6, lane = tid & 63;
    int m0 = (m_base + ml) * 128;
    int wr = wave >> 1, wc = wave & 1;
    int r15 = lane & 15, c = lane >> 4;

    f32x4 acc[4][4];
#pragma unroll
    for (int mf = 0; mf < 4; ++mf)
#pragma unroll
        for (int nf = 0; nf < 4; ++nf) acc[mf][nf] = (f32x4){0.f, 0.f, 0.f, 0.f};

    auto stageX = [&](int k0, char* dst) {
        if constexpr (SRC == 0) stage16_f32(Xf, m0, M - 1, k0, dst, tid);
        else                    stage16(X16, m0, M - 1, k0, dst, tid);
    };

    stageX(0, smem);
    stage16(Wt, n_blk * 128, 511, 0, smem + 8192, tid);
    __syncthreads();

    for (int t = 0; t < 8; ++t) {
        int buf = t & 1;
        if (t < 7) {
            char* nb2 = smem + (buf ^ 1) * 16384;
            stageX((t + 1) * 32, nb2);
            stage16(Wt, n_blk * 128, 511, (t + 1) * 32, nb2 + 8192, tid);
        }
        const char* At = smem + buf * 16384;
        const char* Bt = At + 8192;
        f16x8 af[4], bf[4];
#pragma unroll
        for (int f = 0; f < 4; ++f) {
            int ar = wr * 64 + f * 16 + r15;
            af[f] = *(const f16x8*)(At + ar * 64 + ((c ^ (ar & 3)) << 4));
            int br_ = wc * 64 + f * 16 + r15;
            bf[f] = *(const f16x8*)(Bt + br_ * 64 + ((c ^ (br_ & 3)) << 4));
        }
#pragma unroll
        for (int mf = 0; mf < 4; ++mf)
#pragma unroll
            for (int nf = 0; nf < 4; ++nf)
                acc[mf][nf] = __builtin_amdgcn_mfma_f32_16x16x32_f16(af[mf], bf[nf], acc[mf][nf], 0, 0, 0);
        __syncthreads();
    }

    int q4 = (lane >> 4) * 4;
#pragma unroll
    for (int nf = 0; nf < 4; ++nf) {
        int n_abs = n_blk * 128 + wc * 64 + nf * 16 + r15;
        bool left = n_abs < 256;
        float bb = left ? bl[n_abs] : br[n_abs - 256];
        int col = n_abs & 255;
#pragma unroll
        for (int mf = 0; mf < 4; ++mf) {
            int rowb = m0 + wr * 64 + mf * 16 + q4;
#pragma unroll
            for (int j = 0; j < 4; ++j) {
                int row = rowb + j;
                if (row < M) {
                    float v = acc[mf][nf][j] + bb;
                    if (left) Af[(size_t)row * 256 + col] = (_Float16)v;
                    else      Bf[(size_t)row * 256 + col] = (_Float16)v;
                }
            }
        }
    }
}

// ---- GATv2 node body: 32-lane groups x 2 edges, 8 gathers in flight,
//      per-group online softmax + single cross-group merge.
template <int MODE>
__device__ __forceinline__ void gat_body(int wid, int lane,
                                         const _Float16* __restrict__ xl,
                                         const _Float16* __restrict__ xr,
                                         const int* __restrict__ beg_,
                                         const int* __restrict__ end_,
                                         const unsigned short* __restrict__ csr,
                                         const float* __restrict__ att,
                                         const float* __restrict__ bias,
                                         _Float16* __restrict__ y16,
                                         const float* __restrict__ Wlin,
                                         const float* __restrict__ blin,
                                         float* __restrict__ out) {
    int g = lane >> 5, li = lane & 31;                 // group, lane-in-group
    int beg = beg_[wid], end = end_[wid];

    f16x8 xr8 = nt_load8(xr + (size_t)wid * 256 + li * 8);   // streaming, read-once
    float4 t0 = ((const float4*)att)[li * 2];
    float4 t1 = ((const float4*)att)[li * 2 + 1];
    f16x2 t01 = {(f16)t0.x, (f16)t0.y}, t23 = {(f16)t0.z, (f16)t0.w};
    f16x2 t45 = {(f16)t1.x, (f16)t1.y}, t67 = {(f16)t1.z, (f16)t1.w};
    const f16 ng = (f16)NEG;
    const f16x8 n8 = {ng, ng, ng, ng, ng, ng, ng, ng};

    float m = -INFINITY, ssum = 0.f;
    float acc[8] = {0.f, 0.f, 0.f, 0.f, 0.f, 0.f, 0.f, 0.f};

    auto step = [&](f16x8 a, bool valid) {
        f16x8 v = a + xr8;
        f16x8 lk = __builtin_elementwise_max(v, v * n8);
#ifdef HAVE_FDOT2
        f16x2 q;
        q[0] = lk[0]; q[1] = lk[1];
        float dot = __builtin_amdgcn_fdot2(q, t01, 0.f, false);
        q[0] = lk[2]; q[1] = lk[3];
        dot = __builtin_amdgcn_fdot2(q, t23, dot, false);
        q[0] = lk[4]; q[1] = lk[5];
        dot = __builtin_amdgcn_fdot2(q, t45, dot, false);
        q[0] = lk[6]; q[1] = lk[7];
        dot = __builtin_amdgcn_fdot2(q, t67, dot, false);
#else
        float dot = (float)lk[0] * (float)t01[0] + (float)lk[1] * (float)t01[1] +
                    (float)lk[2] * (float)t23[0] + (float)lk[3] * (float)t23[1] +
                    (float)lk[4] * (float)t45[0] + (float)lk[5] * (float)t45[1] +
                    (float)lk[6] * (float)t67[0] + (float)lk[7] * (float)t67[1];
#endif
#pragma unroll
        for (int off = 16; off > 0; off >>= 1) dot += __shfl_xor(dot, off);
        if (valid) {
            if (dot > m + 8.f) {            // rare after warm-up
                float sc = __expf(m - dot); // m=-inf first edge -> 0
                ssum = ssum * sc + 1.f;
#pragma unroll
                for (int i = 0; i < 8; ++i) acc[i] = acc[i] * sc + (float)a[i];
                m = dot;
            } else {                        // p bounded by e^8
                float p = __expf(dot - m);
                ssum += p;
#pragma unroll
                for (int i = 0; i < 8; ++i) acc[i] += p * (float)a[i];
            }
        }
    };

    int j = beg;
    for (; j + 16 <= end; j += 16) {        // 8 rows in flight per group
        f16x8 a[8];
#pragma unroll
        for (int u = 0; u < 8; ++u) {
            int s = csr[j + 2 * u + g];
            a[u] = ((const f16x8*)(xl + (size_t)s * 256))[li];
        }
#pragma unroll
        for (int u = 0; u < 8; ++u) step(a[u], true);
    }
    if (j + 8 <= end) {
        f16x8 a[4];
#pragma unroll
        for (int u = 0; u < 4; ++u) {
            int s = csr[j + 2 * u + g];
            a[u] = ((const f16x8*)(xl + (size_t)s * 256))[li];
        }
#pragma unroll
        for (int u = 0; u < 4; ++u) step(a[u], true);
        j += 8;
    }
    for (; j < end; j += 2) {
        int e = j + g;
        int s = csr[e < end ? e : end - 1];
        f16x8 a = ((const f16x8*)(xl + (size_t)s * 256))[li];
        step(a, e < end);
    }

    // ---- merge the two group states
    float m_o = __shfl_xor(m, 32);
    float s_o = __shfl_xor(ssum, 32);
    float ms = fmaxf(m, m_o);
    float wa = __expf(m - ms), wb = __expf(m_o - ms);
    float inv = 1.f / (ssum * wa + s_o * wb);
    float4 bb0 = ((const float4*)bias)[li * 2];
    float4 bb1 = ((const float4*)bias)[li * 2 + 1];
    float bbv[8] = {bb0.x, bb0.y, bb0.z, bb0.w, bb1.x, bb1.y, bb1.z, bb1.w};
    float o8[8];
#pragma unroll
    for (int i = 0; i < 8; ++i) {
        float ao = __shfl_xor(acc[i], 32);
        float o = (acc[i] * wa + ao * wb) * inv + bbv[i];
        o8[i] = o > 0.f ? o : NEG * o;
    }

    if (MODE == 0) {
        if (g == 0) {
            f16x8 w;
#pragma unroll
            for (int i = 0; i < 8; ++i) w[i] = (f16)o8[i];
            nt_store8(y16 + (size_t)wid * 256 + li * 8, w);   // streaming write-once
        }
    } else {
        float z0 = 0.f, z1 = 0.f;
#pragma unroll
        for (int p = 0; p < 4; ++p) {
            float4 q = ((const float4*)Wlin)[li * 4 + p];
            z0 += o8[2 * p] * q.x + o8[2 * p + 1] * q.z;
            z1 += o8[2 * p] * q.y + o8[2 * p + 1] * q.w;
        }
#pragma unroll
        for (int off = 16; off > 0; off >>= 1) {
            z0 += __shfl_xor(z0, off);
            z1 += __shfl_xor(z1, off);
        }
        if (lane == 0) {
            z0 += blin[0];
            z1 += blin[1];
            float mx = fmaxf(z0, z1);
            float lse = mx + logf(expf(z0 - mx) + expf(z1 - mx));
            out[(size_t)wid * 2 + 0] = z0 - lse;
            out[(size_t)wid * 2 + 1] = z1 - lse;
        }
    }
}

// ==================== merged: binA (blocks < 2*binAx) || convert_w (rest) ==========
__global__ __launch_bounds__(256) void conv_binA(const int* __restrict__ src0,
                                                 const int* __restrict__ dst0,
                                                 const int* __restrict__ src1,
                                                 const int* __restrict__ dst1,
                                                 int Ereal, int EP, int nb, int binAx,
                                                 int* __restrict__ bkt_next,
                                                 unsigned* __restrict__ bucketBuf,
                                                 const float* __restrict__ Wl0,
                                                 const float* __restrict__ Wr0,
                                                 const float* __restrict__ Wl1,
                                                 const float* __restrict__ Wr1,
                                                 _Float16* __restrict__ Wt) {
    int blk = blockIdx.x;
    if (blk >= 2 * binAx) {
        // ---- convert_w: transposed combined fp16 weights, both layers ----
        int cb = blk - 2 * binAx;
        int l = cb >> 9;
        int idx = (cb & 511) * 256 + threadIdx.x;      // n*256 + k
        int n = idx >> 8, k = idx & 255;
        const float* Wl = l ? Wl1 : Wl0;
        const float* Wr = l ? Wr1 : Wr0;
        float v = (n < 256) ? Wl[k * 256 + n] : Wr[k * 256 + (n - 256)];
        Wt[(size_t)l * 512 * 256 + idx] = (_Float16)v;
        return;
    }
    // ---- binA: bin edges by dst>>8 into CAP-sized buckets ----
    __shared__ int hist[NB_MAX], base[NB_MAX], ofs[NB_MAX];
    int l = blk / binAx;
    int c0 = (blk % binAx) * 4096;
    for (int i = threadIdx.x; i < nb; i += 256) hist[i] = 0;
    __syncthreads();
    const int* src = l ? src1 : src0;
    const int* dst = l ? dst1 : dst0;
    int dcache[16];
#pragma unroll
    for (int k = 0; k < 16; ++k) {
        int i = c0 + k * 256 + threadIdx.x;
        int d = -1;
        if (i < EP) d = (i < Ereal) ? dst[i] : (i - Ereal);
        dcache[k] = d;
        if (d >= 0) atomicAdd(&hist[d >> 8], 1);
    }
    __syncthreads();
    for (int i = threadIdx.x; i < nb; i += 256) {
        base[i] = hist[i] ? atomicAdd(&bkt_next[l * nb + i], hist[i]) : 0;
        ofs[i] = 0;
    }
    __syncthreads();
#pragma unroll
    for (int k = 0; k < 16; ++k) {
        int i = c0 + k * 256 + threadIdx.x;
        int d = dcache[k];
        if (d >= 0) {
            int s = (i < Ereal) ? src[i] : (i - Ereal);
            int bk = d >> 8;
            int pos = base[bk] + atomicAdd(&ofs[bk], 1);
            bucketBuf[(size_t)(l * nb + bk) * CAP + pos] = (unsigned)s | ((unsigned)(d & 255) << 16);
        }
    }
}

// ==================== merged: binB (blocks 0..2*nb) || gemm layer-0 (rest) ==========
__global__ __launch_bounds__(256) void binB_gemm0(const unsigned* __restrict__ bucketBuf,
                                                  const int* __restrict__ bkt_cnt,
                                                  int nb, int N,
                                                  int* __restrict__ beg,
                                                  int* __restrict__ end_,
                                                  unsigned short* __restrict__ csr16,
                                                  const float* __restrict__ Xf,
                                                  const _Float16* __restrict__ Wt,
                                                  const float* __restrict__ bl,
                                                  const float* __restrict__ br,
                                                  _Float16* __restrict__ Af,
                                                  _Float16* __restrict__ Bf,
                                                  int M, int m_tiles) {
    __shared__ char smem[32768];
    int blk = blockIdx.x;
    if (blk < 2 * nb) {
        int* hist = (int*)smem;
        int* sh   = (int*)(smem + 1024);
        int* nxt  = (int*)(smem + 2048);
        int l = blk / nb, b = blk % nb, t = threadIdx.x;
        int cnt = bkt_cnt[l * nb + b];
        const unsigned* buf = bucketBuf + (size_t)(l * nb + b) * CAP;
        unsigned short* csrL = csr16 + (size_t)l * nb * CAP;
        hist[t] = 0;
        __syncthreads();
        for (int i = t; i < cnt; i += 256)
            atomicAdd(&hist[buf[i] >> 16], 1);
        __syncthreads();
        int h = hist[t];
        sh[t] = h;
        __syncthreads();
        for (int o = 1; o < 256; o <<= 1) {
            int x = (t >= o) ? sh[t - o] : 0;
            __syncthreads();
            sh[t] += x;
            __syncthreads();
        }
        int excl = sh[t] - h;
        nxt[t] = excl;
        int d = b * 256 + t;
        if (d < N) {
            beg[(size_t)l * N + d] = b * CAP + excl;
            end_[(size_t)l * N + d] = b * CAP + excl + h;
        }
        __syncthreads();
        for (int i = t; i < cnt; i += 256) {
            unsigned v = buf[i];
            int pos = b * CAP + atomicAdd(&nxt[v >> 16], 1);
            csrL[pos] = (unsigned short)(v & 0xFFFFu);
        }
        return;
    }
    gemm_body<0>(smem, blk - 2 * nb, 0, m_tiles, Xf, nullptr, Wt, bl, br, Af, Bf, M);
}

// ---- gat0 part A (nodes [0, H)) ----
__global__ __launch_bounds__(256) void gat0_A(const _Float16* __restrict__ xl,
                                              const _Float16* __restrict__ xr,
                                              const int* __restrict__ beg_,
                                              const int* __restrict__ end_,
                                              const unsigned short* __restrict__ csr,
                                              const float* __restrict__ att,
                                              const float* __restrict__ bias,
                                              _Float16* __restrict__ y16, int H) {
    int wid = (int)((blockIdx.x * (size_t)blockDim.x + threadIdx.x) >> 6);
    if (wid >= H) return;
    gat_body<0>(wid, threadIdx.x & 63, xl, xr, beg_, end_, csr, att, bias,
                y16, nullptr, nullptr, nullptr);
}

// ---- merged: gat0 part B (nodes [H, N)) || gemm1 part A (rows [0, H)) ----
__global__ __launch_bounds__(256) void gat0B_gemm1A(const _Float16* __restrict__ xl,
                                                    const _Float16* __restrict__ xr,
                                                    const int* __restrict__ beg_,
                                                    const int* __restrict__ end_,
                                                    const unsigned short* __restrict__ csr,
                                                    const float* __restrict__ att,
                                                    const float* __restrict__ bias,
                                                    _Float16* __restrict__ y16,
                                                    int H, int n, int nbB,
                                                    const _Float16* __restrict__ Wt1,
                                                    const float* __restrict__ bl1,
                                                    const float* __restrict__ br1,
                                                    _Float16* __restrict__ Af2,
                                                    _Float16* __restrict__ Bf2,
                                                    int m_tilesA) {
    __shared__ char smem[32768];
    int blk = blockIdx.x;
    if (blk < nbB) {
        int wid = H + (int)(((size_t)blk * blockDim.x + threadIdx.x) >> 6);
        if (wid >= n) return;
        gat_body<0>(wid, threadIdx.x & 63, xl, xr, beg_, end_, csr, att, bias,
                    y16, nullptr, nullptr, nullptr);
        return;
    }
    gemm_body<1>(smem, blk - nbB, 0, m_tilesA, nullptr, y16, Wt1, bl1, br1, Af2, Bf2, n);
}

// ---- gemm1 part B (rows [H, N)) ----
__global__ __launch_bounds__(256) void gemm1_B(const _Float16* __restrict__ X16,
                                               const _Float16* __restrict__ Wt,
                                               const float* __restrict__ bl,
                                               const float* __restrict__ br,
                                               _Float16* __restrict__ Af,
                                               _Float16* __restrict__ Bf,
                                               int M, int m_base, int m_tiles) {
    __shared__ char smem[32768];
    gemm_body<1>(smem, blockIdx.x, m_base, m_tiles, nullptr, X16, Wt, bl, br, Af, Bf, M);
}

// ---- gat1 + fused head ----
__global__ __launch_bounds__(256) void gat1(const _Float16* __restrict__ xl,
                                            const _Float16* __restrict__ xr,
                                            const int* __restrict__ beg_,
                                            const int* __restrict__ end_,
                                            const unsigned short* __restrict__ csr,
                                            const float* __restrict__ att,
                                            const float* __restrict__ bias,
                                            const float* __restrict__ Wlin,
                                            const float* __restrict__ blin,
                                            float* __restrict__ out, int n) {
    int wid = (int)((blockIdx.x * (size_t)blockDim.x + threadIdx.x) >> 6);
    if (wid >= n) return;
    gat_body<1>(wid, threadIdx.x & 63, xl, xr, beg_, end_, csr, att, bias,
                nullptr, Wlin, blin, out);
}

extern "C" void kernel_launch(void* const* d_in, const int* in_sizes, int n_in,
                              void* d_out, int out_size, void* d_ws, size_t ws_size,
                              hipStream_t stream) {
    const float* fts   = (const float*)d_in[0];
    const int*   graph = (const int*)d_in[1];
    const float* Wl0 = (const float*)d_in[2];
    const float* Wr0 = (const float*)d_in[3];
    const float* bl0 = (const float*)d_in[4];
    const float* br0 = (const float*)d_in[5];
    const float* att0 = (const float*)d_in[6];
    const float* b0  = (const float*)d_in[7];
    const float* Wl1 = (const float*)d_in[8];
    const float* Wr1 = (const float*)d_in[9];
    const float* bl1 = (const float*)d_in[10];
    const float* br1 = (const float*)d_in[11];
    const float* att1 = (const float*)d_in[12];
    const float* b1  = (const float*)d_in[13];
    const float* Wlin = (const float*)d_in[14];
    const float* blin = (const float*)d_in[15];

    int N = out_size / 2;                                   // 40000
    long T = in_sizes[0] / ((long)N * 256);                 // 4
    long E = in_sizes[1] / (2 * T);                         // 640000
    int EP = (int)E + N;
    int nb = (N + 255) / 256;                               // 157 buckets

    char* ws = (char*)d_ws;
    size_t off = 0;
    auto alloc = [&](size_t bytes) -> void* {
        void* p = ws + off;
        off += (bytes + 255) & ~(size_t)255;
        return p;
    };
    _Float16* Af  = (_Float16*)alloc((size_t)N * 256 * 2);  // layer0 xl
    _Float16* Bf  = (_Float16*)alloc((size_t)N * 256 * 2);  // layer0 xr
    _Float16* Af2 = (_Float16*)alloc((size_t)N * 256 * 2);  // layer1 xl
    _Float16* Bf2 = (_Float16*)alloc((size_t)N * 256 * 2);  // layer1 xr
    _Float16* Y16 = (_Float16*)alloc((size_t)N * 256 * 2);  // layer-0 output
    _Float16* Wt  = (_Float16*)alloc((size_t)2 * 512 * 256 * 2);
    int* beg      = (int*)alloc((size_t)2 * N * 4);
    int* end_     = (int*)alloc((size_t)2 * N * 4);
    unsigned short* csr16 = (unsigned short*)alloc((size_t)2 * nb * CAP * 2);
    unsigned* bucketBuf = (unsigned*)alloc((size_t)2 * nb * CAP * 4);
    int* bkt_next = (int*)alloc((size_t)2 * nb * 4);
    (void)ws_size; (void)n_in;

    int Mb = (N + 127) / 128;                               // 313
    int MbA = (Mb * 3 / 4) & ~7;                            // 232 (multiple of 8)
    int H = MbA * 128;                                      // 29696
    int gemm_blocks  = ((Mb + 7) / 8) * 8 * 4;              // 1280 (full)
    int gemmA_blocks = MbA * 4;                             // 928
    int MbBcnt = Mb - MbA;                                  // 81
    int gemmB_blocks = ((MbBcnt + 7) / 8) * 8 * 4;          // 352
    int binAx = (EP + 4095) / 4096;                         // 167
    int gat0A_blocks = (H + 3) / 4;
    int gat0B_blocks = (N - H + 3) / 4;
    int node_blocks = (N + 3) / 4;

    const int* src0 = graph;
    const int* dst0 = graph + E;
    const int* srcL = graph + (T - 1) * 2 * E;
    const int* dstL = graph + (T - 1) * 2 * E + E;

    // 1. zero bucket counters (1.3 KB) + merged {binA || weight convert}
    hipMemsetAsync(bkt_next, 0, (size_t)2 * nb * 4, stream);
    conv_binA<<<2 * binAx + 1024, 256, 0, stream>>>(src0, dst0, srcL, dstL,
                                                    (int)E, EP, nb, binAx,
                                                    bkt_next, bucketBuf,
                                                    Wl0, Wr0, Wl1, Wr1, Wt);
    // 2. merged: per-bucket counting sort || layer-0 GEMM
    binB_gemm0<<<2 * nb + gemm_blocks, 256, 0, stream>>>(bucketBuf, bkt_next, nb, N,
                                                         beg, end_, csr16,
                                                         fts, Wt, bl0, br0, Af, Bf, N, Mb);
    // 3. layer-0 node pass, part A (nodes [0,H))
    gat0_A<<<gat0A_blocks, 256, 0, stream>>>(Af, Bf, beg, end_, csr16, att0, b0, Y16, H);
    // 4. merged: layer-0 node pass part B || layer-1 GEMM part A (rows [0,H))
    gat0B_gemm1A<<<gat0B_blocks + gemmA_blocks, 256, 0, stream>>>(
        Af, Bf, beg, end_, csr16, att0, b0, Y16, H, N, gat0B_blocks,
        Wt + (size_t)512 * 256, bl1, br1, Af2, Bf2, MbA);
    // 5. layer-1 GEMM part B (rows [H,N))
    gemm1_B<<<gemmB_blocks, 256, 0, stream>>>(Y16, Wt + (size_t)512 * 256,
                                              bl1, br1, Af2, Bf2, N, MbA, MbBcnt);
    // 6. layer-1 node pass + fused head
    gat1<<<node_blocks, 256, 0, stream>>>(Af2, Bf2, beg + N, end_ + N,
                                          csr16 + (size_t)nb * CAP, att1, b1,
                                          Wlin, blin, (float*)d_out, N);
}

// Round 14
// 235.495 us; speedup vs baseline: 1.1533x; 1.1533x over previous
//
#include <hip/hip_runtime.h>
#include <hip/hip_bf16.h>
#include <math.h>

#define NEG 0.2f
#define NB_MAX 256
#define CAP 5120

typedef float f32x4 __attribute__((ext_vector_type(4)));
typedef _Float16 f16;
typedef _Float16 f16x2 __attribute__((ext_vector_type(2)));
typedef _Float16 f16x8 __attribute__((ext_vector_type(8)));

#if defined(__has_builtin)
#if __has_builtin(__builtin_amdgcn_fdot2)
#define HAVE_FDOT2 1
#endif
#endif

typedef __attribute__((address_space(3))) void as3_void;
typedef __attribute__((address_space(1))) const void as1_void;

__device__ __forceinline__ void gl_lds16(const void* g, void* l) {
    __builtin_amdgcn_global_load_lds((as1_void*)g, (as3_void*)l, 16, 0, 0);
}

// ---- stage one 128-row x 32-k fp16 tile (8KB, [128][64B] rows, slot^(row&3)
//      swizzle) into LDS via global_load_lds with pre-swizzled source.
__device__ __forceinline__ void stage16(const _Float16* __restrict__ src,
                                        int row_base, int row_max, int k0,
                                        char* lds, int tid) {
#pragma unroll
    for (int q = 0; q < 2; ++q) {
        int off = q * 4096 + tid * 16;
        int row = off >> 6;
        int slot = (off >> 4) & 3;
        int se = slot ^ (row & 3);
        int grow = row_base + row;
        if (grow > row_max) grow = row_max;
        gl_lds16(src + (size_t)grow * 256 + k0 + se * 8,
                 lds + q * 4096 + (tid >> 6) * 1024);   // wave-uniform LDS base
    }
}

// ---- same tile from an fp32 source: reg-staged load + cvt + ds_write (swizzled)
__device__ __forceinline__ void stage16_f32(const float* __restrict__ X,
                                            int row_base, int row_max, int k0,
                                            char* lds, int tid) {
#pragma unroll
    for (int u = 0; u < 4; ++u) {
        int unit = u * 256 + tid;                      // 8B units
        int r = unit >> 3, hu = unit & 7;
        int slot = hu >> 1, sub = (hu & 1) * 8;
        int se = slot ^ (r & 3);
        int grow = row_base + r;
        if (grow > row_max) grow = row_max;
        float4 v = *(const float4*)(X + (size_t)grow * 256 + k0 + se * 8 + (hu & 1) * 4);
        f16x2 p0 = {(f16)v.x, (f16)v.y};
        f16x2 p1 = {(f16)v.z, (f16)v.w};
        uint2 w;
        w.x = __builtin_bit_cast(unsigned, p0);
        w.y = __builtin_bit_cast(unsigned, p1);
        *(uint2*)(lds + r * 64 + slot * 16 + sub) = w;
    }
}

// ---- fp16 MFMA GEMM body: [M,256] x [256,512] -> Af f16 (+bl), Bf f16 (+br)
//      128x128 tile, 4 waves, BK=32, double-buffered 32KB LDS, XCD-aware remap.
template <int SRC>
__device__ __forceinline__ void gemm_body(char* smem, int b,
                                          const float* __restrict__ Xf,
                                          const _Float16* __restrict__ X16,
                                          const _Float16* __restrict__ Wt,
                                          const float* __restrict__ bl,
                                          const float* __restrict__ br,
                                          _Float16* __restrict__ Af,
                                          _Float16* __restrict__ Bf, int M) {
    int Mb = (M + 127) >> 7;
    int cx = b & 7, rr = b >> 3;                      // cx = XCD slot
    int m_blk = (rr >> 2) * 8 + cx;
    int n_blk = rr & 3;
    if (m_blk >= Mb) return;
    int tid = threadIdx.x;
    int wave = tid >> 6, lane = tid & 63;
    int m0 = m_blk * 128;
    int wr = wave >> 1, wc = wave & 1;
    int r15 = lane & 15, c = lane >> 4;

    f32x4 acc[4][4];
#pragma unroll
    for (int mf = 0; mf < 4; ++mf)
#pragma unroll
        for (int nf = 0; nf < 4; ++nf) acc[mf][nf] = (f32x4){0.f, 0.f, 0.f, 0.f};

    auto stageX = [&](int k0, char* dst) {
        if constexpr (SRC == 0) stage16_f32(Xf, m0, M - 1, k0, dst, tid);
        else                    stage16(X16, m0, M - 1, k0, dst, tid);
    };

    stageX(0, smem);
    stage16(Wt, n_blk * 128, 511, 0, smem + 8192, tid);
    __syncthreads();

    for (int t = 0; t < 8; ++t) {
        int buf = t & 1;
        if (t < 7) {
            char* nb2 = smem + (buf ^ 1) * 16384;
            stageX((t + 1) * 32, nb2);
            stage16(Wt, n_blk * 128, 511, (t + 1) * 32, nb2 + 8192, tid);
        }
        const char* At = smem + buf * 16384;
        const char* Bt = At + 8192;
        f16x8 af[4], bf[4];
#pragma unroll
        for (int f = 0; f < 4; ++f) {
            int ar = wr * 64 + f * 16 + r15;
            af[f] = *(const f16x8*)(At + ar * 64 + ((c ^ (ar & 3)) << 4));
            int br_ = wc * 64 + f * 16 + r15;
            bf[f] = *(const f16x8*)(Bt + br_ * 64 + ((c ^ (br_ & 3)) << 4));
        }
#pragma unroll
        for (int mf = 0; mf < 4; ++mf)
#pragma unroll
            for (int nf = 0; nf < 4; ++nf)
                acc[mf][nf] = __builtin_amdgcn_mfma_f32_16x16x32_f16(af[mf], bf[nf], acc[mf][nf], 0, 0, 0);
        __syncthreads();
    }

    int q4 = (lane >> 4) * 4;
#pragma unroll
    for (int nf = 0; nf < 4; ++nf) {
        int n_abs = n_blk * 128 + wc * 64 + nf * 16 + r15;
        bool left = n_abs < 256;
        float bb = left ? bl[n_abs] : br[n_abs - 256];
        int col = n_abs & 255;
#pragma unroll
        for (int mf = 0; mf < 4; ++mf) {
            int rowb = m0 + wr * 64 + mf * 16 + q4;
#pragma unroll
            for (int j = 0; j < 4; ++j) {
                int row = rowb + j;
                if (row < M) {
                    float v = acc[mf][nf][j] + bb;
                    if (left) Af[(size_t)row * 256 + col] = (_Float16)v;
                    else      Bf[(size_t)row * 256 + col] = (_Float16)v;
                }
            }
        }
    }
}

// ==================== merged: binA (blocks < 2*binAx) || convert_w (rest) ==========
__global__ __launch_bounds__(256) void conv_binA(const int* __restrict__ src0,
                                                 const int* __restrict__ dst0,
                                                 const int* __restrict__ src1,
                                                 const int* __restrict__ dst1,
                                                 int Ereal, int EP, int nb, int binAx,
                                                 int* __restrict__ bkt_next,
                                                 unsigned* __restrict__ bucketBuf,
                                                 const float* __restrict__ Wl0,
                                                 const float* __restrict__ Wr0,
                                                 const float* __restrict__ Wl1,
                                                 const float* __restrict__ Wr1,
                                                 _Float16* __restrict__ Wt) {
    int blk = blockIdx.x;
    if (blk >= 2 * binAx) {
        // ---- convert_w: transposed combined fp16 weights, both layers ----
        int cb = blk - 2 * binAx;
        int l = cb >> 9;
        int idx = (cb & 511) * 256 + threadIdx.x;      // n*256 + k
        int n = idx >> 8, k = idx & 255;
        const float* Wl = l ? Wl1 : Wl0;
        const float* Wr = l ? Wr1 : Wr0;
        float v = (n < 256) ? Wl[k * 256 + n] : Wr[k * 256 + (n - 256)];
        Wt[(size_t)l * 512 * 256 + idx] = (_Float16)v;
        return;
    }
    // ---- binA: bin edges by dst>>8 into CAP-sized buckets ----
    __shared__ int hist[NB_MAX], base[NB_MAX], ofs[NB_MAX];
    int l = blk / binAx;
    int c0 = (blk % binAx) * 4096;
    for (int i = threadIdx.x; i < nb; i += 256) hist[i] = 0;
    __syncthreads();
    const int* src = l ? src1 : src0;
    const int* dst = l ? dst1 : dst0;
    int dcache[16];
#pragma unroll
    for (int k = 0; k < 16; ++k) {
        int i = c0 + k * 256 + threadIdx.x;
        int d = -1;
        if (i < EP) d = (i < Ereal) ? dst[i] : (i - Ereal);
        dcache[k] = d;
        if (d >= 0) atomicAdd(&hist[d >> 8], 1);
    }
    __syncthreads();
    for (int i = threadIdx.x; i < nb; i += 256) {
        base[i] = hist[i] ? atomicAdd(&bkt_next[l * nb + i], hist[i]) : 0;
        ofs[i] = 0;
    }
    __syncthreads();
#pragma unroll
    for (int k = 0; k < 16; ++k) {
        int i = c0 + k * 256 + threadIdx.x;
        int d = dcache[k];
        if (d >= 0) {
            int s = (i < Ereal) ? src[i] : (i - Ereal);
            int bk = d >> 8;
            int pos = base[bk] + atomicAdd(&ofs[bk], 1);
            bucketBuf[(size_t)(l * nb + bk) * CAP + pos] = (unsigned)s | ((unsigned)(d & 255) << 16);
        }
    }
}

// ==================== merged: binB (blocks 0..2*nb) || gemm layer-0 (rest) ==========
__global__ __launch_bounds__(256) void binB_gemm0(const unsigned* __restrict__ bucketBuf,
                                                  const int* __restrict__ bkt_cnt,
                                                  int nb, int N,
                                                  int* __restrict__ beg,
                                                  int* __restrict__ end_,
                                                  unsigned short* __restrict__ csr16,
                                                  const float* __restrict__ Xf,
                                                  const _Float16* __restrict__ Wt,
                                                  const float* __restrict__ bl,
                                                  const float* __restrict__ br,
                                                  _Float16* __restrict__ Af,
                                                  _Float16* __restrict__ Bf, int M) {
    __shared__ char smem[32768];
    int blk = blockIdx.x;
    if (blk < 2 * nb) {
        int* hist = (int*)smem;
        int* sh   = (int*)(smem + 1024);
        int* nxt  = (int*)(smem + 2048);
        int l = blk / nb, b = blk % nb, t = threadIdx.x;
        int cnt = bkt_cnt[l * nb + b];
        const unsigned* buf = bucketBuf + (size_t)(l * nb + b) * CAP;
        unsigned short* csrL = csr16 + (size_t)l * nb * CAP;
        hist[t] = 0;
        __syncthreads();
        for (int i = t; i < cnt; i += 256)
            atomicAdd(&hist[buf[i] >> 16], 1);
        __syncthreads();
        int h = hist[t];
        sh[t] = h;
        __syncthreads();
        for (int o = 1; o < 256; o <<= 1) {
            int x = (t >= o) ? sh[t - o] : 0;
            __syncthreads();
            sh[t] += x;
            __syncthreads();
        }
        int excl = sh[t] - h;
        nxt[t] = excl;
        int d = b * 256 + t;
        if (d < N) {
            beg[(size_t)l * N + d] = b * CAP + excl;
            end_[(size_t)l * N + d] = b * CAP + excl + h;
        }
        __syncthreads();
        for (int i = t; i < cnt; i += 256) {
            unsigned v = buf[i];
            int pos = b * CAP + atomicAdd(&nxt[v >> 16], 1);
            csrL[pos] = (unsigned short)(v & 0xFFFFu);
        }
        return;
    }
    gemm_body<0>(smem, blk - 2 * nb, Xf, nullptr, Wt, bl, br, Af, Bf, M);
}

// ---- standalone layer-1 GEMM (fp16 X) ----
__global__ __launch_bounds__(256) void mfma_gemm1(const _Float16* __restrict__ X16,
                                                  const _Float16* __restrict__ Wt,
                                                  const float* __restrict__ bl,
                                                  const float* __restrict__ br,
                                                  _Float16* __restrict__ Af,
                                                  _Float16* __restrict__ Bf, int M) {
    __shared__ char smem[32768];
    gemm_body<1>(smem, blockIdx.x, nullptr, X16, Wt, bl, br, Af, Bf, M);
}

// ---- fused GATv2 node pass: one wave64 per node, 32-lane groups x 2 edges,
//      8 gathers in flight, per-group online softmax + single cross-group merge.
//      MODE 0: write y fp16 (feeds next GEMM + next gather); MODE 1: fused head.
template <int MODE>
__global__ __launch_bounds__(256) void gat_node(const _Float16* __restrict__ xl,
                                                const _Float16* __restrict__ xr,
                                                const int* __restrict__ beg_,
                                                const int* __restrict__ end_,
                                                const unsigned short* __restrict__ csr,
                                                const float* __restrict__ att,
                                                const float* __restrict__ bias,
                                                _Float16* __restrict__ y16,
                                                const float* __restrict__ Wlin,
                                                const float* __restrict__ blin,
                                                float* __restrict__ out, int n) {
    int wid = (int)((blockIdx.x * (size_t)blockDim.x + threadIdx.x) >> 6);
    int lane = threadIdx.x & 63;
    if (wid >= n) return;
    int g = lane >> 5, li = lane & 31;                 // group, lane-in-group
    int beg = beg_[wid], end = end_[wid];

    f16x8 xr8 = ((const f16x8*)(xr + (size_t)wid * 256))[li];  // ch 8li..8li+7
    float4 t0 = ((const float4*)att)[li * 2];
    float4 t1 = ((const float4*)att)[li * 2 + 1];
    f16x2 t01 = {(f16)t0.x, (f16)t0.y}, t23 = {(f16)t0.z, (f16)t0.w};
    f16x2 t45 = {(f16)t1.x, (f16)t1.y}, t67 = {(f16)t1.z, (f16)t1.w};
    const f16 ng = (f16)NEG;
    const f16x8 n8 = {ng, ng, ng, ng, ng, ng, ng, ng};

    float m = -INFINITY, ssum = 0.f;
    float acc[8] = {0.f, 0.f, 0.f, 0.f, 0.f, 0.f, 0.f, 0.f};

    auto step = [&](f16x8 a, bool valid) {
        f16x8 v = a + xr8;
        f16x8 lk = __builtin_elementwise_max(v, v * n8);
#ifdef HAVE_FDOT2
        f16x2 q;
        q[0] = lk[0]; q[1] = lk[1];
        float dot = __builtin_amdgcn_fdot2(q, t01, 0.f, false);
        q[0] = lk[2]; q[1] = lk[3];
        dot = __builtin_amdgcn_fdot2(q, t23, dot, false);
        q[0] = lk[4]; q[1] = lk[5];
        dot = __builtin_amdgcn_fdot2(q, t45, dot, false);
        q[0] = lk[6]; q[1] = lk[7];
        dot = __builtin_amdgcn_fdot2(q, t67, dot, false);
#else
        float dot = (float)lk[0] * (float)t01[0] + (float)lk[1] * (float)t01[1] +
                    (float)lk[2] * (float)t23[0] + (float)lk[3] * (float)t23[1] +
                    (float)lk[4] * (float)t45[0] + (float)lk[5] * (float)t45[1] +
                    (float)lk[6] * (float)t67[0] + (float)lk[7] * (float)t67[1];
#endif
#pragma unroll
        for (int off = 16; off > 0; off >>= 1) dot += __shfl_xor(dot, off);
        if (valid) {
            if (dot > m + 8.f) {            // rare after warm-up
                float sc = __expf(m - dot); // m=-inf first edge -> 0
                ssum = ssum * sc + 1.f;
#pragma unroll
                for (int i = 0; i < 8; ++i) acc[i] = acc[i] * sc + (float)a[i];
                m = dot;
            } else {                        // p bounded by e^8
                float p = __expf(dot - m);
                ssum += p;
#pragma unroll
                for (int i = 0; i < 8; ++i) acc[i] += p * (float)a[i];
            }
        }
    };

    int j = beg;
    for (; j + 16 <= end; j += 16) {        // 8 rows in flight per group
        f16x8 a[8];
#pragma unroll
        for (int u = 0; u < 8; ++u) {
            int s = csr[j + 2 * u + g];
            a[u] = ((const f16x8*)(xl + (size_t)s * 256))[li];
        }
#pragma unroll
        for (int u = 0; u < 8; ++u) step(a[u], true);
    }
    if (j + 8 <= end) {
        f16x8 a[4];
#pragma unroll
        for (int u = 0; u < 4; ++u) {
            int s = csr[j + 2 * u + g];
            a[u] = ((const f16x8*)(xl + (size_t)s * 256))[li];
        }
#pragma unroll
        for (int u = 0; u < 4; ++u) step(a[u], true);
        j += 8;
    }
    for (; j < end; j += 2) {
        int e = j + g;
        int s = csr[e < end ? e : end - 1];
        f16x8 a = ((const f16x8*)(xl + (size_t)s * 256))[li];
        step(a, e < end);
    }

    // ---- merge the two group states
    float m_o = __shfl_xor(m, 32);
    float s_o = __shfl_xor(ssum, 32);
    float ms = fmaxf(m, m_o);
    float wa = __expf(m - ms), wb = __expf(m_o - ms);
    float inv = 1.f / (ssum * wa + s_o * wb);
    float4 bb0 = ((const float4*)bias)[li * 2];
    float4 bb1 = ((const float4*)bias)[li * 2 + 1];
    float bbv[8] = {bb0.x, bb0.y, bb0.z, bb0.w, bb1.x, bb1.y, bb1.z, bb1.w};
    float o8[8];
#pragma unroll
    for (int i = 0; i < 8; ++i) {
        float ao = __shfl_xor(acc[i], 32);
        float o = (acc[i] * wa + ao * wb) * inv + bbv[i];
        o8[i] = o > 0.f ? o : NEG * o;
    }

    if (MODE == 0) {
        if (g == 0) {
            f16x8 w;
#pragma unroll
            for (int i = 0; i < 8; ++i) w[i] = (f16)o8[i];
            ((f16x8*)(y16 + (size_t)wid * 256))[li] = w;
        }
    } else {
        float z0 = 0.f, z1 = 0.f;
#pragma unroll
        for (int p = 0; p < 4; ++p) {
            float4 q = ((const float4*)Wlin)[li * 4 + p];
            z0 += o8[2 * p] * q.x + o8[2 * p + 1] * q.z;
            z1 += o8[2 * p] * q.y + o8[2 * p + 1] * q.w;
        }
#pragma unroll
        for (int off = 16; off > 0; off >>= 1) {
            z0 += __shfl_xor(z0, off);
            z1 += __shfl_xor(z1, off);
        }
        if (lane == 0) {
            z0 += blin[0];
            z1 += blin[1];
            float mx = fmaxf(z0, z1);
            float lse = mx + logf(expf(z0 - mx) + expf(z1 - mx));
            out[(size_t)wid * 2 + 0] = z0 - lse;
            out[(size_t)wid * 2 + 1] = z1 - lse;
        }
    }
}

extern "C" void kernel_launch(void* const* d_in, const int* in_sizes, int n_in,
                              void* d_out, int out_size, void* d_ws, size_t ws_size,
                              hipStream_t stream) {
    const float* fts   = (const float*)d_in[0];
    const int*   graph = (const int*)d_in[1];
    const float* Wl0 = (const float*)d_in[2];
    const float* Wr0 = (const float*)d_in[3];
    const float* bl0 = (const float*)d_in[4];
    const float* br0 = (const float*)d_in[5];
    const float* att0 = (const float*)d_in[6];
    const float* b0  = (const float*)d_in[7];
    const float* Wl1 = (const float*)d_in[8];
    const float* Wr1 = (const float*)d_in[9];
    const float* bl1 = (const float*)d_in[10];
    const float* br1 = (const float*)d_in[11];
    const float* att1 = (const float*)d_in[12];
    const float* b1  = (const float*)d_in[13];
    const float* Wlin = (const float*)d_in[14];
    const float* blin = (const float*)d_in[15];

    int N = out_size / 2;                                   // 40000
    long T = in_sizes[0] / ((long)N * 256);                 // 4
    long E = in_sizes[1] / (2 * T);                         // 640000
    int EP = (int)E + N;
    int nb = (N + 255) / 256;                               // 157 buckets

    char* ws = (char*)d_ws;
    size_t off = 0;
    auto alloc = [&](size_t bytes) -> void* {
        void* p = ws + off;
        off += (bytes + 255) & ~(size_t)255;
        return p;
    };
    _Float16* Af  = (_Float16*)alloc((size_t)N * 256 * 2);  // xl (fp16)
    _Float16* Bf  = (_Float16*)alloc((size_t)N * 256 * 2);  // xr (fp16)
    _Float16* Y16 = (_Float16*)alloc((size_t)N * 256 * 2);  // layer-0 output
    _Float16* Wt  = (_Float16*)alloc((size_t)2 * 512 * 256 * 2);
    int* beg      = (int*)alloc((size_t)2 * N * 4);
    int* end_     = (int*)alloc((size_t)2 * N * 4);
    unsigned short* csr16 = (unsigned short*)alloc((size_t)2 * nb * CAP * 2);
    unsigned* bucketBuf = (unsigned*)alloc((size_t)2 * nb * CAP * 4);
    int* bkt_next = (int*)alloc((size_t)2 * nb * 4);
    (void)ws_size; (void)n_in;

    int Mb = (N + 127) / 128;                               // 313
    int gemm_blocks = ((Mb + 7) / 8) * 8 * 4;               // XCD-padded grid
    int binAx = (EP + 4095) / 4096;                         // 167
    int node_blocks = (N + 3) / 4;

    const int* src0 = graph;
    const int* dst0 = graph + E;
    const int* srcL = graph + (T - 1) * 2 * E;
    const int* dstL = graph + (T - 1) * 2 * E + E;

    // 1. zero bucket counters (1.3 KB) + merged {binA || weight convert}
    hipMemsetAsync(bkt_next, 0, (size_t)2 * nb * 4, stream);
    conv_binA<<<2 * binAx + 1024, 256, 0, stream>>>(src0, dst0, srcL, dstL,
                                                    (int)E, EP, nb, binAx,
                                                    bkt_next, bucketBuf,
                                                    Wl0, Wr0, Wl1, Wr1, Wt);
    // 2. merged: per-bucket counting sort (both layers) || layer-0 GEMM
    binB_gemm0<<<2 * nb + gemm_blocks, 256, 0, stream>>>(bucketBuf, bkt_next, nb, N,
                                                         beg, end_, csr16,
                                                         fts, Wt, bl0, br0, Af, Bf, N);
    // 3. layer-0 node pass
    gat_node<0><<<node_blocks, 256, 0, stream>>>(Af, Bf, beg, end_, csr16, att0, b0,
                                                 Y16, nullptr, nullptr, nullptr, N);
    // 4. layer-1 GEMM
    mfma_gemm1<<<gemm_blocks, 256, 0, stream>>>(Y16, Wt + (size_t)512 * 256,
                                                bl1, br1, Af, Bf, N);
    // 5. layer-1 node pass + fused head
    gat_node<1><<<node_blocks, 256, 0, stream>>>(Af, Bf, beg + N, end_ + N,
                                                 csr16 + (size_t)nb * CAP, att1, b1,
                                                 nullptr, Wlin, blin, (float*)d_out, N);
}